// Round 5
// baseline (1270.938 us; speedup 1.0000x reference)
//
#include <hip/hip_runtime.h>
#include <hip/hip_bf16.h>
#include <math.h>

// Problem constants (fixed by the reference)
#define NN 50000
#define EE 400000
#define TT 4
#define DIN 64
#define DD 128
#define BB 64
#define STEPS 8
#define KAGG 544    // 512 (T*D) + 4 (per-type counts for b_msg) + 28 pad -> 17*32
#define KGATES 256  // [a | h]
#define NGATES 512  // [r_sum, z_sum, i_n, h_n]
#define NBIN (4 * NN)             // (dst, etype) bins
#define NBLK ((NBIN + 255) / 256) // 782 scan blocks
#define ASTRIDE 136               // a_s row stride in shorts (128 + 8 pad)

typedef __attribute__((ext_vector_type(8))) short bf16x8;
typedef __attribute__((ext_vector_type(4))) float f32x4;
typedef __attribute__((address_space(3))) void lds_void;
typedef __attribute__((address_space(1))) void glob_void;

__device__ inline float bf2f(__hip_bfloat16 x) { return __bfloat162float(x); }

// ---------------------------------------------------------------- init h (zero-pad 64->128)
__global__ void k_init_h(const float* __restrict__ feat, float* __restrict__ h,
                         float* __restrict__ h1, __hip_bfloat16* __restrict__ hb) {
    int idx = blockIdx.x * blockDim.x + threadIdx.x;
    if (idx >= NN * DD) return;
    int v = idx >> 7, d = idx & 127;
    float val = (d < DIN) ? feat[v * DIN + d] : 0.0f;
    h[idx] = val;
    h1[idx] = val;
    hb[idx] = __float2bfloat16(val);
}

__global__ void k_zero_i32(int* __restrict__ p, int n) {
    int idx = blockIdx.x * blockDim.x + threadIdx.x;
    if (idx < n) p[idx] = 0;
}
__global__ void k_zero_f32(float* __restrict__ p, int n) {
    int idx = blockIdx.x * blockDim.x + threadIdx.x;
    if (idx < n) p[idx] = 0.0f;
}

// ---------------------------------------------------------------- CSR build by (dst,type)
__global__ void k_hist(const int* __restrict__ dst, const int* __restrict__ etype,
                       int* __restrict__ deg2) {
    int e = blockIdx.x * blockDim.x + threadIdx.x;
    if (e < EE) atomicAdd(&deg2[dst[e] * 4 + etype[e]], 1);
}

// ---- 3-pass device-wide exclusive scan over deg2[NBIN] ----
__global__ __launch_bounds__(256) void k_scan_bsum(const int* __restrict__ deg2,
                                                   int* __restrict__ bsum) {
    __shared__ int red[256];
    int tid = threadIdx.x;
    int i = blockIdx.x * 256 + tid;
    int v = (i < NBIN) ? deg2[i] : 0;
    red[tid] = v;
    __syncthreads();
#pragma unroll
    for (int s = 128; s > 0; s >>= 1) {
        if (tid < s) red[tid] += red[tid + s];
        __syncthreads();
    }
    if (tid == 0) bsum[blockIdx.x] = red[0];
}

__global__ __launch_bounds__(1024) void k_scan_boff(const int* __restrict__ bsum,
                                                    int* __restrict__ boff) {
    __shared__ int s[1024];
    int tid = threadIdx.x;
    int v = (tid < NBLK) ? bsum[tid] : 0;
    s[tid] = v;
    __syncthreads();
    for (int d = 1; d < 1024; d <<= 1) {
        int t = (tid >= d) ? s[tid - d] : 0;
        __syncthreads();
        s[tid] += t;
        __syncthreads();
    }
    if (tid < NBLK) boff[tid] = s[tid] - v;  // exclusive
}

__global__ __launch_bounds__(256) void k_scan_final(const int* __restrict__ deg2,
                                                    const int* __restrict__ boff,
                                                    int* __restrict__ off2,
                                                    int* __restrict__ cursor) {
    __shared__ int s[256];
    int tid = threadIdx.x;
    int i = blockIdx.x * 256 + tid;
    int v = (i < NBIN) ? deg2[i] : 0;
    s[tid] = v;
    __syncthreads();
#pragma unroll
    for (int d = 1; d < 256; d <<= 1) {
        int t = (tid >= d) ? s[tid - d] : 0;
        __syncthreads();
        s[tid] += t;
        __syncthreads();
    }
    int excl = boff[blockIdx.x] + s[tid] - v;
    if (i < NBIN) {
        off2[i] = excl;
        cursor[i] = excl;
        if (i == NBIN - 1) off2[NBIN] = excl + v;  // == EE
    }
}

__global__ void k_fill(const int* __restrict__ dst, const int* __restrict__ src,
                       const int* __restrict__ etype, int* __restrict__ cursor,
                       int* __restrict__ csr_src) {
    int e = blockIdx.x * blockDim.x + threadIdx.x;
    if (e < EE) {
        int pos = atomicAdd(&cursor[dst[e] * 4 + etype[e]], 1);
        csr_src[pos] = src[e];
    }
}

// counts columns of g (cols 512..543) are constant across steps: write once
__global__ void k_counts(const int* __restrict__ off2, __hip_bfloat16* __restrict__ g) {
    int idx = blockIdx.x * blockDim.x + threadIdx.x;
    if (idx >= NN * 16) return;
    int v = idx >> 4, j = idx & 15;
    float x = 0.0f, y = 0.0f;
    if (j < 2) {
        int t0 = 2 * j;
        x = (float)(off2[4 * v + t0 + 1] - off2[4 * v + t0]);
        y = (float)(off2[4 * v + t0 + 2] - off2[4 * v + t0 + 1]);
    }
    __hip_bfloat162 o;
    o.x = __float2bfloat16(x);
    o.y = __float2bfloat16(y);
    ((__hip_bfloat162*)(g + (size_t)v * KAGG))[256 + j] = o;
}

// ---------------------------------------------------------------- weight prep (once/call)
__global__ void k_prep_w(const float* __restrict__ Wm, const float* __restrict__ bm,
                         const float* __restrict__ wih, const float* __restrict__ bih,
                         const float* __restrict__ whh, const float* __restrict__ bhh,
                         __hip_bfloat16* __restrict__ WcatT, __hip_bfloat16* __restrict__ WgT,
                         float* __restrict__ bias512) {
    int idx = blockIdx.x * blockDim.x + threadIdx.x;
    if (idx < 128 * KAGG) {
        int n = idx / KAGG, k = idx % KAGG;
        float v = 0.0f;
        if (k < 512) {
            int t = k >> 7, d = k & 127;
            v = Wm[(t << 14) + (d << 7) + n];
        } else if (k < 516) {
            v = bm[((k - 512) << 7) + n];
        }
        WcatT[idx] = __float2bfloat16(v);
    }
    int j = idx - 128 * KAGG;
    if (j >= 0 && j < NGATES * KGATES) {
        int n = j >> 8, k = j & 255;
        float v;
        if (k < 128) {
            v = (n < 384) ? wih[k * 384 + n] : 0.0f;
        } else {
            int d = k - 128;
            v = (n < 256) ? whh[d * 384 + n] : ((n < 384) ? 0.0f : whh[d * 384 + n - 128]);
        }
        WgT[j] = __float2bfloat16(v);
    }
    int b = idx - (128 * KAGG + NGATES * KGATES);
    if (b >= 0 && b < NGATES) {
        float v;
        if (b < 256) v = bih[b] + bhh[b];
        else if (b < 384) v = bih[b];
        else v = bhh[b - 128];
        bias512[b] = v;
    }
}

// ---------------------------------------------------------------- per-type aggregation
// one wave per node; lane owns dims (2*lane, 2*lane+1); type-sorted CSR -> no masking
__global__ __launch_bounds__(256) void k_agg(const __hip_bfloat16* __restrict__ hb,
                                             const int* __restrict__ off2,
                                             const int* __restrict__ csr_src,
                                             __hip_bfloat16* __restrict__ g) {
    int node = (blockIdx.x * blockDim.x + threadIdx.x) >> 6;
    int lane = threadIdx.x & 63;
    if (node >= NN) return;
    const __hip_bfloat162* hb2 = (const __hip_bfloat162*)hb;
    __hip_bfloat162* grow = (__hip_bfloat162*)(g + (size_t)node * KAGG);
    int b0 = off2[4 * node];
    int b1 = off2[4 * node + 1];
    int b2 = off2[4 * node + 2];
    int b3 = off2[4 * node + 3];
    int b4 = off2[4 * node + 4];
    int beg[5] = {b0, b1, b2, b3, b4};
#pragma unroll
    for (int t = 0; t < TT; ++t) {
        float ax = 0.0f, ay = 0.0f;
        int p = beg[t], e = beg[t + 1];
        for (; p + 1 < e; p += 2) {  // 2-way unroll for load-latency overlap
            int s0 = csr_src[p];
            int s1 = csr_src[p + 1];
            __hip_bfloat162 v0 = hb2[(size_t)s0 * 64 + lane];
            __hip_bfloat162 v1 = hb2[(size_t)s1 * 64 + lane];
            ax += bf2f(v0.x) + bf2f(v1.x);
            ay += bf2f(v0.y) + bf2f(v1.y);
        }
        if (p < e) {
            int s0 = csr_src[p];
            __hip_bfloat162 v0 = hb2[(size_t)s0 * 64 + lane];
            ax += bf2f(v0.x);
            ay += bf2f(v0.y);
        }
        __hip_bfloat162 o;
        o.x = __float2bfloat16(ax);
        o.y = __float2bfloat16(ay);
        grow[t * 64 + lane] = o;
    }
}

// ---------------------------------------------------------------- fused step kernel
// Per 128-row block:
//   Phase 1: a[128][128] = g[rows,544] @ WcatT^T   (MFMA, staged LDS) -> a_s (LDS, bf16)
//   Phase 2: gates[128][512] = [a | h] @ WgT^T + bias -> in-register GRU -> h out
// Phase-2 A-fragments: a_s (k<128) or direct 16B global loads of h_bf (k>=128).
// Phase-2 B-fragments: direct 16B global loads of WgT (256KB, L2-resident).
__global__ __launch_bounds__(256) void k_step(const __hip_bfloat16* __restrict__ g,
                                              const __hip_bfloat16* __restrict__ WcatT,
                                              const __hip_bfloat16* __restrict__ h_bf,
                                              const __hip_bfloat16* __restrict__ WgT,
                                              const float* __restrict__ bias512,
                                              const float* __restrict__ hp,
                                              float* __restrict__ ho,
                                              __hip_bfloat16* __restrict__ hbo) {
    __shared__ short As[128 * 32];
    __shared__ short Bs[128 * 32];
    __shared__ short a_s[128 * ASTRIDE];
    const int tid = threadIdx.x;
    const int lane = tid & 63;
    const int wave = tid >> 6;
    const int row0 = blockIdx.x * 128;
    const int wm = (wave & 1) * 64;
    const int wn = (wave >> 1) * 64;
    const int quad = lane >> 4;
    const int m16 = lane & 15;

    // ---------------- phase 1: a = g @ WcatT^T ----------------
    {
        f32x4 acc[4][4];
#pragma unroll
        for (int t = 0; t < 4; ++t)
#pragma unroll
            for (int u = 0; u < 4; ++u) acc[t][u] = (f32x4){0.f, 0.f, 0.f, 0.f};

        for (int k0 = 0; k0 < KAGG; k0 += 32) {
#pragma unroll
            for (int i = 0; i < 2; ++i) {
                int s = tid + i * 256;
                int srow = s >> 2;
                int kp = (s & 3) * 8;
                int grow = row0 + srow;
                if (grow >= NN) grow = NN - 1;
                const __hip_bfloat16* ga = g + (size_t)grow * KAGG + k0 + kp;
                __builtin_amdgcn_global_load_lds((const glob_void*)ga,
                                                 (lds_void*)&As[(wave * 64 + i * 256) * 8], 16, 0, 0);
                const __hip_bfloat16* gb = WcatT + (size_t)srow * KAGG + k0 + kp;
                __builtin_amdgcn_global_load_lds((const glob_void*)gb,
                                                 (lds_void*)&Bs[(wave * 64 + i * 256) * 8], 16, 0, 0);
            }
            __syncthreads();
            bf16x8 af[4], bfr[4];
#pragma unroll
            for (int t = 0; t < 4; ++t)
                af[t] = *(bf16x8*)&As[(wm + t * 16 + m16) * 32 + quad * 8];
#pragma unroll
            for (int u = 0; u < 4; ++u)
                bfr[u] = *(bf16x8*)&Bs[(wn + u * 16 + m16) * 32 + quad * 8];
#pragma unroll
            for (int t = 0; t < 4; ++t)
#pragma unroll
                for (int u = 0; u < 4; ++u)
                    acc[t][u] = __builtin_amdgcn_mfma_f32_16x16x32_bf16(af[t], bfr[u], acc[t][u], 0, 0, 0);
            __syncthreads();
        }
        // deposit a (bf16) into padded LDS
#pragma unroll
        for (int t = 0; t < 4; ++t)
#pragma unroll
            for (int u = 0; u < 4; ++u) {
                int col = wn + u * 16 + m16;
#pragma unroll
                for (int r = 0; r < 4; ++r) {
                    int row = wm + t * 16 + quad * 4 + r;
                    __hip_bfloat16 b = __float2bfloat16(acc[t][u][r]);
                    a_s[row * ASTRIDE + col] = *(short*)&b;
                }
            }
    }
    __syncthreads();

    // ---------------- phase 2: gates + GRU ----------------
    for (int cy = 0; cy < 4; ++cy) {
        f32x4 acc[2][4][2];  // [row-tile][gate][col-tile]
#pragma unroll
        for (int t = 0; t < 2; ++t)
#pragma unroll
            for (int gg = 0; gg < 4; ++gg)
#pragma unroll
                for (int c = 0; c < 2; ++c) acc[t][gg][c] = (f32x4){0.f, 0.f, 0.f, 0.f};

        for (int k0 = 0; k0 < KGATES; k0 += 32) {
            bf16x8 af[2], bfr[4][2];
#pragma unroll
            for (int t = 0; t < 2; ++t) {
                int row = wave * 32 + t * 16 + m16;
                if (k0 < 128) {
                    af[t] = *(bf16x8*)&a_s[row * ASTRIDE + k0 + quad * 8];
                } else {
                    int grow = row0 + row;  // may exceed NN by <128: stays inside ws
                    af[t] = *(const bf16x8*)(h_bf + (size_t)grow * DD + (k0 - 128) + quad * 8);
                }
            }
#pragma unroll
            for (int gg = 0; gg < 4; ++gg)
#pragma unroll
                for (int c = 0; c < 2; ++c) {
                    int col = (gg << 7) + cy * 32 + c * 16 + m16;
                    bfr[gg][c] = *(const bf16x8*)(WgT + (size_t)col * KGATES + k0 + quad * 8);
                }
#pragma unroll
            for (int t = 0; t < 2; ++t)
#pragma unroll
                for (int gg = 0; gg < 4; ++gg)
#pragma unroll
                    for (int c = 0; c < 2; ++c)
                        acc[t][gg][c] = __builtin_amdgcn_mfma_f32_16x16x32_bf16(
                            af[t], bfr[gg][c], acc[t][gg][c], 0, 0, 0);
        }
        // epilogue: in-register GRU
#pragma unroll
        for (int c = 0; c < 2; ++c) {
            int d = cy * 32 + c * 16 + m16;
            float brs = bias512[d];
            float bzs = bias512[128 + d];
            float bin_ = bias512[256 + d];
            float bhn = bias512[384 + d];
#pragma unroll
            for (int t = 0; t < 2; ++t) {
                int rbase = row0 + wave * 32 + t * 16 + quad * 4;
#pragma unroll
                for (int r = 0; r < 4; ++r) {
                    int row = rbase + r;
                    if (row >= NN) continue;
                    float rs = acc[t][0][c][r] + brs;
                    float zs = acc[t][1][c][r] + bzs;
                    float inn = acc[t][2][c][r] + bin_;
                    float hnn = acc[t][3][c][r] + bhn;
                    float rr = 1.0f / (1.0f + __expf(-rs));
                    float zz = 1.0f / (1.0f + __expf(-zs));
                    float ng = tanhf(inn + rr * hnn);
                    float hv = hp[(size_t)row * DD + d];
                    float o = (1.0f - zz) * ng + zz * hv;
                    ho[(size_t)row * DD + d] = o;
                    hbo[(size_t)row * DD + d] = __float2bfloat16(o);
                }
            }
        }
    }
}

// ---------------------------------------------------------------- readout (n2g is sorted)
__global__ __launch_bounds__(128) void k_readout(const float* __restrict__ h,
                                                 const float* __restrict__ h1,
                                                 const int* __restrict__ n2g,
                                                 float* __restrict__ feats) {
    const int CHN = 64;
    int d = threadIdx.x;
    int v0 = blockIdx.x * CHN;
    if (v0 >= NN) return;
    int v1 = v0 + CHN;
    if (v1 > NN) v1 = NN;
    float sum = 0.0f;
    int cur = n2g[v0];
    for (int v = v0; v < v1; ++v) {
        int gph = n2g[v];
        if (gph != cur) {
            atomicAdd(&feats[cur * DD + d], sum);
            sum = 0.0f;
            cur = gph;
        }
        sum += h[(size_t)v * DD + d] + h1[(size_t)v * DD + d];
    }
    atomicAdd(&feats[cur * DD + d], sum);
}

// ---------------------------------------------------------------- classifier
__global__ void k_cls(const float* __restrict__ feats, const float* __restrict__ Wc,
                      const float* __restrict__ bc, float* __restrict__ out) {
    int t = threadIdx.x;
    if (t >= BB * 2) return;
    int b = t >> 1, c = t & 1;
    float s = bc[c];
    for (int d = 0; d < DD; ++d) s += feats[b * DD + d] * Wc[d * 2 + c];
    out[t] = s;
}

// ================================================================ launcher
extern "C" void kernel_launch(void* const* d_in, const int* in_sizes, int n_in, void* d_out,
                              int out_size, void* d_ws, size_t ws_size, hipStream_t stream) {
    const float* features = (const float*)d_in[0];
    const int* src = (const int*)d_in[1];
    const int* dst = (const int*)d_in[2];
    const int* etype = (const int*)d_in[3];
    const int* n2g = (const int*)d_in[4];
    const float* W_msg = (const float*)d_in[5];
    const float* b_msg = (const float*)d_in[6];
    const float* w_ih = (const float*)d_in[7];
    const float* b_ih = (const float*)d_in[8];
    const float* w_hh = (const float*)d_in[9];
    const float* b_hh = (const float*)d_in[10];
    const float* W_cls = (const float*)d_in[11];
    const float* b_cls = (const float*)d_in[12];
    float* out = (float*)d_out;

    char* ws = (char*)d_ws;
    size_t o = 0;
    auto alloc = [&](size_t bytes) {
        o = (o + 255) & ~(size_t)255;
        void* p = ws + o;
        o += bytes;
        return p;
    };
    int* deg2 = (int*)alloc(sizeof(int) * NBIN);
    int* off2 = (int*)alloc(sizeof(int) * (NBIN + 1));
    int* cursor = (int*)alloc(sizeof(int) * NBIN);
    int* bsum = (int*)alloc(sizeof(int) * NBLK);
    int* boff = (int*)alloc(sizeof(int) * NBLK);
    int* csr_src = (int*)alloc(sizeof(int) * EE);
    __hip_bfloat16* WcatT = (__hip_bfloat16*)alloc(sizeof(__hip_bfloat16) * 128 * KAGG);
    __hip_bfloat16* WgT = (__hip_bfloat16*)alloc(sizeof(__hip_bfloat16) * NGATES * KGATES);
    float* bias512 = (float*)alloc(sizeof(float) * NGATES);
    float* h0 = (float*)alloc(sizeof(float) * (size_t)NN * DD);
    float* h1p = (float*)alloc(sizeof(float) * (size_t)NN * DD);
    float* hini = (float*)alloc(sizeof(float) * (size_t)NN * DD);
    __hip_bfloat16* hbfA = (__hip_bfloat16*)alloc(sizeof(__hip_bfloat16) * (size_t)NN * DD);
    __hip_bfloat16* hbfB = (__hip_bfloat16*)alloc(sizeof(__hip_bfloat16) * (size_t)NN * DD);
    __hip_bfloat16* g = (__hip_bfloat16*)alloc(sizeof(__hip_bfloat16) * (size_t)NN * KAGG);
    float* feats = (float*)alloc(sizeof(float) * BB * DD);

    // setup
    k_init_h<<<(NN * DD + 255) / 256, 256, 0, stream>>>(features, h0, hini, hbfA);
    k_zero_i32<<<(NBIN + 255) / 256, 256, 0, stream>>>(deg2, NBIN);
    k_zero_f32<<<(BB * DD + 255) / 256, 256, 0, stream>>>(feats, BB * DD);
    k_hist<<<(EE + 255) / 256, 256, 0, stream>>>(dst, etype, deg2);
    k_scan_bsum<<<NBLK, 256, 0, stream>>>(deg2, bsum);
    k_scan_boff<<<1, 1024, 0, stream>>>(bsum, boff);
    k_scan_final<<<NBLK, 256, 0, stream>>>(deg2, boff, off2, cursor);
    k_fill<<<(EE + 255) / 256, 256, 0, stream>>>(dst, src, etype, cursor, csr_src);
    k_counts<<<(NN * 16 + 255) / 256, 256, 0, stream>>>(off2, g);
    {
        int prep_n = 128 * KAGG + NGATES * KGATES + NGATES;
        k_prep_w<<<(prep_n + 255) / 256, 256, 0, stream>>>(W_msg, b_msg, w_ih, b_ih, w_hh,
                                                           b_hh, WcatT, WgT, bias512);
    }

    const int MT = (NN + 127) / 128;  // 391 row tiles
    float* hc = h0;
    float* hx = h1p;
    __hip_bfloat16* hbc = hbfA;
    __hip_bfloat16* hbx = hbfB;
    for (int s = 0; s < STEPS; ++s) {
        k_agg<<<(NN * 64 + 255) / 256, 256, 0, stream>>>(hbc, off2, csr_src, g);
        k_step<<<MT, 256, 0, stream>>>(g, WcatT, hbc, WgT, bias512, hc, hx, hbx);
        float* tf = hc; hc = hx; hx = tf;
        __hip_bfloat16* tb = hbc; hbc = hbx; hbx = tb;
    }
    k_readout<<<(NN + 63) / 64, 128, 0, stream>>>(hc, hini, n2g, feats);
    k_cls<<<1, 128, 0, stream>>>(feats, W_cls, b_cls, out);
}

// Round 6
// 1018.436 us; speedup vs baseline: 1.2479x; 1.2479x over previous
//
#include <hip/hip_runtime.h>
#include <hip/hip_bf16.h>
#include <math.h>

// Problem constants (fixed by the reference)
#define NN 50000
#define EE 400000
#define TT 4
#define DIN 64
#define DD 128
#define BB 64
#define STEPS 8
#define KAGG 544    // 512 (T*D) + 4 (per-type counts for b_msg) + 28 pad -> 17*32
#define KGATES 256  // [a | h]
#define NGATES 512  // [r_sum, z_sum, i_n, h_n]
#define NBIN (4 * NN)             // (dst, etype) bins
#define NBLK ((NBIN + 255) / 256) // 782 scan blocks
#define AHS 264                   // ah row stride in shorts (256 + 8 pad -> 2-way banks)
#define MT64 ((NN + 63) / 64)     // 782 step blocks

typedef __attribute__((ext_vector_type(8))) short bf16x8;
typedef __attribute__((ext_vector_type(4))) float f32x4;
typedef __attribute__((address_space(3))) void lds_void;
typedef __attribute__((address_space(1))) void glob_void;

__device__ inline float bf2f(__hip_bfloat16 x) { return __bfloat162float(x); }

// ---------------------------------------------------------------- init (zero-pad 64->128)
// h kept ONLY in bf16 (hb); hini fp32 for residual+readout precision
__global__ void k_init_h(const float* __restrict__ feat, float* __restrict__ h1,
                         __hip_bfloat16* __restrict__ hb) {
    int idx = blockIdx.x * blockDim.x + threadIdx.x;
    if (idx >= NN * DD) return;
    int v = idx >> 7, d = idx & 127;
    float val = (d < DIN) ? feat[v * DIN + d] : 0.0f;
    h1[idx] = val;
    hb[idx] = __float2bfloat16(val);
}

__global__ void k_zero_i32(int* __restrict__ p, int n) {
    int idx = blockIdx.x * blockDim.x + threadIdx.x;
    if (idx < n) p[idx] = 0;
}
__global__ void k_zero_f32(float* __restrict__ p, int n) {
    int idx = blockIdx.x * blockDim.x + threadIdx.x;
    if (idx < n) p[idx] = 0.0f;
}

// ---------------------------------------------------------------- CSR build by (dst,type)
__global__ void k_hist(const int* __restrict__ dst, const int* __restrict__ etype,
                       int* __restrict__ deg2) {
    int e = blockIdx.x * blockDim.x + threadIdx.x;
    if (e < EE) atomicAdd(&deg2[dst[e] * 4 + etype[e]], 1);
}

// ---- 3-pass device-wide exclusive scan over deg2[NBIN] ----
__global__ __launch_bounds__(256) void k_scan_bsum(const int* __restrict__ deg2,
                                                   int* __restrict__ bsum) {
    __shared__ int red[256];
    int tid = threadIdx.x;
    int i = blockIdx.x * 256 + tid;
    int v = (i < NBIN) ? deg2[i] : 0;
    red[tid] = v;
    __syncthreads();
#pragma unroll
    for (int s = 128; s > 0; s >>= 1) {
        if (tid < s) red[tid] += red[tid + s];
        __syncthreads();
    }
    if (tid == 0) bsum[blockIdx.x] = red[0];
}

__global__ __launch_bounds__(1024) void k_scan_boff(const int* __restrict__ bsum,
                                                    int* __restrict__ boff) {
    __shared__ int s[1024];
    int tid = threadIdx.x;
    int v = (tid < NBLK) ? bsum[tid] : 0;
    s[tid] = v;
    __syncthreads();
    for (int d = 1; d < 1024; d <<= 1) {
        int t = (tid >= d) ? s[tid - d] : 0;
        __syncthreads();
        s[tid] += t;
        __syncthreads();
    }
    if (tid < NBLK) boff[tid] = s[tid] - v;  // exclusive
}

__global__ __launch_bounds__(256) void k_scan_final(const int* __restrict__ deg2,
                                                    const int* __restrict__ boff,
                                                    int* __restrict__ off2,
                                                    int* __restrict__ cursor) {
    __shared__ int s[256];
    int tid = threadIdx.x;
    int i = blockIdx.x * 256 + tid;
    int v = (i < NBIN) ? deg2[i] : 0;
    s[tid] = v;
    __syncthreads();
#pragma unroll
    for (int d = 1; d < 256; d <<= 1) {
        int t = (tid >= d) ? s[tid - d] : 0;
        __syncthreads();
        s[tid] += t;
        __syncthreads();
    }
    int excl = boff[blockIdx.x] + s[tid] - v;
    if (i < NBIN) {
        off2[i] = excl;
        cursor[i] = excl;
        if (i == NBIN - 1) off2[NBIN] = excl + v;  // == EE
    }
}

__global__ void k_fill(const int* __restrict__ dst, const int* __restrict__ src,
                       const int* __restrict__ etype, int* __restrict__ cursor,
                       int* __restrict__ csr_src) {
    int e = blockIdx.x * blockDim.x + threadIdx.x;
    if (e < EE) {
        int pos = atomicAdd(&cursor[dst[e] * 4 + etype[e]], 1);
        csr_src[pos] = src[e];
    }
}

// counts columns of g (cols 512..543) are constant across steps: write once
__global__ void k_counts(const int* __restrict__ off2, __hip_bfloat16* __restrict__ g) {
    int idx = blockIdx.x * blockDim.x + threadIdx.x;
    if (idx >= NN * 16) return;
    int v = idx >> 4, j = idx & 15;
    float x = 0.0f, y = 0.0f;
    if (j < 2) {
        int t0 = 2 * j;
        x = (float)(off2[4 * v + t0 + 1] - off2[4 * v + t0]);
        y = (float)(off2[4 * v + t0 + 2] - off2[4 * v + t0 + 1]);
    }
    __hip_bfloat162 o;
    o.x = __float2bfloat16(x);
    o.y = __float2bfloat16(y);
    ((__hip_bfloat162*)(g + (size_t)v * KAGG))[256 + j] = o;
}

// ---------------------------------------------------------------- weight prep (once/call)
__global__ void k_prep_w(const float* __restrict__ Wm, const float* __restrict__ bm,
                         const float* __restrict__ wih, const float* __restrict__ bih,
                         const float* __restrict__ whh, const float* __restrict__ bhh,
                         __hip_bfloat16* __restrict__ WcatT, __hip_bfloat16* __restrict__ WgT,
                         float* __restrict__ bias512) {
    int idx = blockIdx.x * blockDim.x + threadIdx.x;
    if (idx < 128 * KAGG) {
        int n = idx / KAGG, k = idx % KAGG;
        float v = 0.0f;
        if (k < 512) {
            int t = k >> 7, d = k & 127;
            v = Wm[(t << 14) + (d << 7) + n];
        } else if (k < 516) {
            v = bm[((k - 512) << 7) + n];
        }
        WcatT[idx] = __float2bfloat16(v);
    }
    int j = idx - 128 * KAGG;
    if (j >= 0 && j < NGATES * KGATES) {
        int n = j >> 8, k = j & 255;
        float v;
        if (k < 128) {
            v = (n < 384) ? wih[k * 384 + n] : 0.0f;
        } else {
            int d = k - 128;
            v = (n < 256) ? whh[d * 384 + n] : ((n < 384) ? 0.0f : whh[d * 384 + n - 128]);
        }
        WgT[j] = __float2bfloat16(v);
    }
    int b = idx - (128 * KAGG + NGATES * KGATES);
    if (b >= 0 && b < NGATES) {
        float v;
        if (b < 256) v = bih[b] + bhh[b];
        else if (b < 384) v = bih[b];
        else v = bhh[b - 128];
        bias512[b] = v;
    }
}

// ---------------------------------------------------------------- per-type aggregation
__global__ __launch_bounds__(256) void k_agg(const __hip_bfloat16* __restrict__ hb,
                                             const int* __restrict__ off2,
                                             const int* __restrict__ csr_src,
                                             __hip_bfloat16* __restrict__ g) {
    int node = (blockIdx.x * blockDim.x + threadIdx.x) >> 6;
    int lane = threadIdx.x & 63;
    if (node >= NN) return;
    const __hip_bfloat162* hb2 = (const __hip_bfloat162*)hb;
    __hip_bfloat162* grow = (__hip_bfloat162*)(g + (size_t)node * KAGG);
    int b0 = off2[4 * node];
    int b1 = off2[4 * node + 1];
    int b2 = off2[4 * node + 2];
    int b3 = off2[4 * node + 3];
    int b4 = off2[4 * node + 4];
    int beg[5] = {b0, b1, b2, b3, b4};
#pragma unroll
    for (int t = 0; t < TT; ++t) {
        float ax = 0.0f, ay = 0.0f;
        int p = beg[t], e = beg[t + 1];
        for (; p + 1 < e; p += 2) {
            int s0 = csr_src[p];
            int s1 = csr_src[p + 1];
            __hip_bfloat162 v0 = hb2[(size_t)s0 * 64 + lane];
            __hip_bfloat162 v1 = hb2[(size_t)s1 * 64 + lane];
            ax += bf2f(v0.x) + bf2f(v1.x);
            ay += bf2f(v0.y) + bf2f(v1.y);
        }
        if (p < e) {
            int s0 = csr_src[p];
            __hip_bfloat162 v0 = hb2[(size_t)s0 * 64 + lane];
            ax += bf2f(v0.x);
            ay += bf2f(v0.y);
        }
        __hip_bfloat162 o;
        o.x = __float2bfloat16(ax);
        o.y = __float2bfloat16(ay);
        grow[t * 64 + lane] = o;
    }
}

// ---------------------------------------------------------------- fused step kernel (64-row)
// Phase 1: a[64][128] = g @ WcatT^T  (MFMA, As/Bs staged) -> ah cols 0..127
// Phase 2: gates = [a|h] @ WgT^T + bias -> in-register GRU -> hbo (bf16)
// ah[64][AHS]: cols 0..127 a, 128..255 h tile; +8-short pad -> 2-way-max LDS banks.
__global__ __launch_bounds__(256) void k_step(const __hip_bfloat16* __restrict__ g,
                                              const __hip_bfloat16* __restrict__ WcatT,
                                              const __hip_bfloat16* __restrict__ WgT,
                                              const float* __restrict__ bias512,
                                              const __hip_bfloat16* __restrict__ hbi,
                                              __hip_bfloat16* __restrict__ hbo) {
    __shared__ short As[64 * 32];    // 4 KB
    __shared__ short Bs[128 * 32];   // 8 KB
    __shared__ short ah[64 * AHS];   // 33 KB
    const int tid = threadIdx.x;
    const int lane = tid & 63;
    const int wave = tid >> 6;
    const int row0 = blockIdx.x * 64;
    const int quad = lane >> 4;
    const int m16 = lane & 15;

    // stage h tile into ah cols 128..255 (register round-trip honors the pad)
#pragma unroll
    for (int i = 0; i < 4; ++i) {
        int s = tid + i * 256;          // 1024 slots of 8 shorts
        int srow = s >> 4;
        int kp = (s & 15) * 8;
        int grow = row0 + srow;
        if (grow >= NN) grow = NN - 1;
        bf16x8 v = *(const bf16x8*)(hbi + (size_t)grow * DD + kp);
        *(bf16x8*)&ah[srow * AHS + 128 + kp] = v;
    }

    // ---------------- phase 1: a = g @ WcatT^T ----------------
    {
        const int wm = (wave & 1) * 32;
        const int wn = (wave >> 1) * 64;
        f32x4 acc[2][4];
#pragma unroll
        for (int t = 0; t < 2; ++t)
#pragma unroll
            for (int u = 0; u < 4; ++u) acc[t][u] = (f32x4){0.f, 0.f, 0.f, 0.f};

        for (int k0 = 0; k0 < KAGG; k0 += 32) {
            {   // A tile 64x32: 256 slots, 1/thread
                int srow = tid >> 2;
                int kp = (tid & 3) * 8;
                int grow = row0 + srow;
                if (grow >= NN) grow = NN - 1;
                __builtin_amdgcn_global_load_lds(
                    (const glob_void*)(g + (size_t)grow * KAGG + k0 + kp),
                    (lds_void*)&As[(wave * 64) * 8], 16, 0, 0);
            }
#pragma unroll
            for (int i = 0; i < 2; ++i) {  // B tile 128x32: 512 slots
                int s = tid + i * 256;
                int srow = s >> 2;
                int kp = (s & 3) * 8;
                __builtin_amdgcn_global_load_lds(
                    (const glob_void*)(WcatT + (size_t)srow * KAGG + k0 + kp),
                    (lds_void*)&Bs[(wave * 64 + i * 256) * 8], 16, 0, 0);
            }
            __syncthreads();
            bf16x8 af[2], bfr[4];
#pragma unroll
            for (int t = 0; t < 2; ++t)
                af[t] = *(bf16x8*)&As[(wm + t * 16 + m16) * 32 + quad * 8];
#pragma unroll
            for (int u = 0; u < 4; ++u)
                bfr[u] = *(bf16x8*)&Bs[(wn + u * 16 + m16) * 32 + quad * 8];
#pragma unroll
            for (int t = 0; t < 2; ++t)
#pragma unroll
                for (int u = 0; u < 4; ++u)
                    acc[t][u] = __builtin_amdgcn_mfma_f32_16x16x32_bf16(af[t], bfr[u], acc[t][u], 0, 0, 0);
            __syncthreads();
        }
        // deposit a (bf16) into ah cols 0..127
#pragma unroll
        for (int t = 0; t < 2; ++t)
#pragma unroll
            for (int u = 0; u < 4; ++u) {
                int col = wn + u * 16 + m16;
#pragma unroll
                for (int r = 0; r < 4; ++r) {
                    int row = wm + t * 16 + quad * 4 + r;
                    __hip_bfloat16 b = __float2bfloat16(acc[t][u][r]);
                    ah[row * AHS + col] = *(short*)&b;
                }
            }
    }
    __syncthreads();

    // ---------------- phase 2: gates + GRU ----------------
    const int rw = wave * 16;  // wave owns 16 rows
    for (int cy = 0; cy < 4; ++cy) {
        f32x4 acc2[4][2];  // [gate][col-16]
#pragma unroll
        for (int gg = 0; gg < 4; ++gg)
#pragma unroll
            for (int c = 0; c < 2; ++c) acc2[gg][c] = (f32x4){0.f, 0.f, 0.f, 0.f};

        for (int k0 = 0; k0 < KGATES; k0 += 32) {
#pragma unroll
            for (int i = 0; i < 2; ++i) {  // B tile 128x32 for this cy slice
                int s = tid + i * 256;
                int srow = s >> 2;
                int kp = (s & 3) * 8;
                int bcol = ((srow >> 5) << 7) + cy * 32 + (srow & 31);
                __builtin_amdgcn_global_load_lds(
                    (const glob_void*)(WgT + (size_t)bcol * KGATES + k0 + kp),
                    (lds_void*)&Bs[(wave * 64 + i * 256) * 8], 16, 0, 0);
            }
            __syncthreads();
            bf16x8 af = *(bf16x8*)&ah[(rw + m16) * AHS + k0 + quad * 8];  // unified a|h
            bf16x8 bfr[4][2];
#pragma unroll
            for (int gg = 0; gg < 4; ++gg)
#pragma unroll
                for (int c = 0; c < 2; ++c)
                    bfr[gg][c] = *(bf16x8*)&Bs[((gg << 5) + c * 16 + m16) * 32 + quad * 8];
#pragma unroll
            for (int gg = 0; gg < 4; ++gg)
#pragma unroll
                for (int c = 0; c < 2; ++c)
                    acc2[gg][c] = __builtin_amdgcn_mfma_f32_16x16x32_bf16(af, bfr[gg][c],
                                                                          acc2[gg][c], 0, 0, 0);
            __syncthreads();
        }
        // epilogue: in-register GRU, h read from ah, write bf16 h only
#pragma unroll
        for (int c = 0; c < 2; ++c) {
            int d = cy * 32 + c * 16 + m16;
            float brs = bias512[d];
            float bzs = bias512[128 + d];
            float bin_ = bias512[256 + d];
            float bhn = bias512[384 + d];
#pragma unroll
            for (int r = 0; r < 4; ++r) {
                int rowl = rw + quad * 4 + r;
                int grow = row0 + rowl;
                if (grow >= NN) continue;
                float rs = acc2[0][c][r] + brs;
                float zs = acc2[1][c][r] + bzs;
                float inn = acc2[2][c][r] + bin_;
                float hnn = acc2[3][c][r] + bhn;
                float rr = 1.0f / (1.0f + __expf(-rs));
                float zz = 1.0f / (1.0f + __expf(-zs));
                float ng = tanhf(inn + rr * hnn);
                short hvs = ah[rowl * AHS + 128 + d];
                float hv = bf2f(*(__hip_bfloat16*)&hvs);
                float o = (1.0f - zz) * ng + zz * hv;
                hbo[(size_t)grow * DD + d] = __float2bfloat16(o);
            }
        }
    }
}

// ---------------------------------------------------------------- readout (n2g is sorted)
__global__ __launch_bounds__(128) void k_readout(const __hip_bfloat16* __restrict__ h,
                                                 const float* __restrict__ h1,
                                                 const int* __restrict__ n2g,
                                                 float* __restrict__ feats) {
    const int CHN = 64;
    int d = threadIdx.x;
    int v0 = blockIdx.x * CHN;
    if (v0 >= NN) return;
    int v1 = v0 + CHN;
    if (v1 > NN) v1 = NN;
    float sum = 0.0f;
    int cur = n2g[v0];
    for (int v = v0; v < v1; ++v) {
        int gph = n2g[v];
        if (gph != cur) {
            atomicAdd(&feats[cur * DD + d], sum);
            sum = 0.0f;
            cur = gph;
        }
        sum += bf2f(h[(size_t)v * DD + d]) + h1[(size_t)v * DD + d];
    }
    atomicAdd(&feats[cur * DD + d], sum);
}

// ---------------------------------------------------------------- classifier
__global__ void k_cls(const float* __restrict__ feats, const float* __restrict__ Wc,
                      const float* __restrict__ bc, float* __restrict__ out) {
    int t = threadIdx.x;
    if (t >= BB * 2) return;
    int b = t >> 1, c = t & 1;
    float s = bc[c];
    for (int d = 0; d < DD; ++d) s += feats[b * DD + d] * Wc[d * 2 + c];
    out[t] = s;
}

// ================================================================ launcher
extern "C" void kernel_launch(void* const* d_in, const int* in_sizes, int n_in, void* d_out,
                              int out_size, void* d_ws, size_t ws_size, hipStream_t stream) {
    const float* features = (const float*)d_in[0];
    const int* src = (const int*)d_in[1];
    const int* dst = (const int*)d_in[2];
    const int* etype = (const int*)d_in[3];
    const int* n2g = (const int*)d_in[4];
    const float* W_msg = (const float*)d_in[5];
    const float* b_msg = (const float*)d_in[6];
    const float* w_ih = (const float*)d_in[7];
    const float* b_ih = (const float*)d_in[8];
    const float* w_hh = (const float*)d_in[9];
    const float* b_hh = (const float*)d_in[10];
    const float* W_cls = (const float*)d_in[11];
    const float* b_cls = (const float*)d_in[12];
    float* out = (float*)d_out;

    char* ws = (char*)d_ws;
    size_t o = 0;
    auto alloc = [&](size_t bytes) {
        o = (o + 255) & ~(size_t)255;
        void* p = ws + o;
        o += bytes;
        return p;
    };
    int* deg2 = (int*)alloc(sizeof(int) * NBIN);
    int* off2 = (int*)alloc(sizeof(int) * (NBIN + 1));
    int* cursor = (int*)alloc(sizeof(int) * NBIN);
    int* bsum = (int*)alloc(sizeof(int) * NBLK);
    int* boff = (int*)alloc(sizeof(int) * NBLK);
    int* csr_src = (int*)alloc(sizeof(int) * EE);
    __hip_bfloat16* WcatT = (__hip_bfloat16*)alloc(sizeof(__hip_bfloat16) * 128 * KAGG);
    __hip_bfloat16* WgT = (__hip_bfloat16*)alloc(sizeof(__hip_bfloat16) * NGATES * KGATES);
    float* bias512 = (float*)alloc(sizeof(float) * NGATES);
    float* hini = (float*)alloc(sizeof(float) * (size_t)NN * DD);
    __hip_bfloat16* hbfA = (__hip_bfloat16*)alloc(sizeof(__hip_bfloat16) * (size_t)NN * DD);
    __hip_bfloat16* hbfB = (__hip_bfloat16*)alloc(sizeof(__hip_bfloat16) * (size_t)NN * DD);
    __hip_bfloat16* g = (__hip_bfloat16*)alloc(sizeof(__hip_bfloat16) * (size_t)NN * KAGG);
    float* feats = (float*)alloc(sizeof(float) * BB * DD);

    // setup
    k_init_h<<<(NN * DD + 255) / 256, 256, 0, stream>>>(features, hini, hbfA);
    k_zero_i32<<<(NBIN + 255) / 256, 256, 0, stream>>>(deg2, NBIN);
    k_zero_f32<<<(BB * DD + 255) / 256, 256, 0, stream>>>(feats, BB * DD);
    k_hist<<<(EE + 255) / 256, 256, 0, stream>>>(dst, etype, deg2);
    k_scan_bsum<<<NBLK, 256, 0, stream>>>(deg2, bsum);
    k_scan_boff<<<1, 1024, 0, stream>>>(bsum, boff);
    k_scan_final<<<NBLK, 256, 0, stream>>>(deg2, boff, off2, cursor);
    k_fill<<<(EE + 255) / 256, 256, 0, stream>>>(dst, src, etype, cursor, csr_src);
    k_counts<<<(NN * 16 + 255) / 256, 256, 0, stream>>>(off2, g);
    {
        int prep_n = 128 * KAGG + NGATES * KGATES + NGATES;
        k_prep_w<<<(prep_n + 255) / 256, 256, 0, stream>>>(W_msg, b_msg, w_ih, b_ih, w_hh,
                                                           b_hh, WcatT, WgT, bias512);
    }

    __hip_bfloat16* hbc = hbfA;
    __hip_bfloat16* hbx = hbfB;
    for (int s = 0; s < STEPS; ++s) {
        k_agg<<<(NN * 64 + 255) / 256, 256, 0, stream>>>(hbc, off2, csr_src, g);
        k_step<<<MT64, 256, 0, stream>>>(g, WcatT, WgT, bias512, hbc, hbx);
        __hip_bfloat16* tb = hbc; hbc = hbx; hbx = tb;
    }
    k_readout<<<(NN + 63) / 64, 128, 0, stream>>>(hbc, hini, n2g, feats);
    k_cls<<<1, 128, 0, stream>>>(feats, W_cls, b_cls, out);
}